// Round 6
// baseline (171.424 us; speedup 1.0000x reference)
//
#include <hip/hip_runtime.h>

// Problem constants
#define DD 64
#define LL 50
#define NB 4096
#define NT 100

typedef __attribute__((ext_vector_type(8))) __bf16 bf16x8;
typedef __attribute__((ext_vector_type(4))) float f32x4;

__device__ __forceinline__ float sigmoidf_(float x) {
    // v_rcp_f32 (~1ulp) instead of precise-division sequence
    return __builtin_amdgcn_rcpf(1.0f + __expf(-x));
}
// HW packed RNE convert: dst.lo = bf16(lo), dst.hi = bf16(hi)
__device__ __forceinline__ unsigned cvtpk(float lo, float hi) {
    unsigned r;
    asm("v_cvt_pk_bf16_f32 %0, %1, %2" : "=v"(r) : "v"(lo), "v"(hi));
    return r;
}
__device__ __forceinline__ bf16x8 cvt8f(const float* f) {
    uint4 r;
    r.x = cvtpk(f[0], f[1]);
    r.y = cvtpk(f[2], f[3]);
    r.z = cvtpk(f[4], f[5]);
    r.w = cvtpk(f[6], f[7]);
    return __builtin_bit_cast(bf16x8, r);
}
// async global->LDS: wave-uniform LDS base + lane*size (gfx950)
__device__ __forceinline__ void glds16(const float* g, float* l) {
    __builtin_amdgcn_global_load_lds(
        (const __attribute__((address_space(1))) void*)g,
        (__attribute__((address_space(3))) void*)l, 16, 0, 0);
}
__device__ __forceinline__ void glds4(const float* g, float* l) {
    __builtin_amdgcn_global_load_lds(
        (const __attribute__((address_space(1))) void*)g,
        (__attribute__((address_space(3))) void*)l, 4, 0, 0);
}

// ===========================================================================
// K_ALL: single fused kernel, one block (4 waves) per b. No k0, no workspace.
//   Phase A0 (one latency window, all streams independent):
//     - 4 glds16 item rows/wave into wave-private sE quadrant (XOR-swizzled)
//     - 7 W2 float4/thread -> regs (scoring prefetch)
//     - b2 glds4 (waves 2,3), user row glds4 -> sUu (wave 1)
//     - ufg/t2 inputs: u16/wu16 float4 + igu scalars (L2-hot small tables)
//     - wb frags straight from f32 Wi + cvtpk (L2-hot, replaces wiB pack)
//   ufg[n]=dot(u,Wu[n])+bu+bi, t2[l]=dot(u,igu[:,l]) computed in-block:
//     4-lane groups, 16 FMA each, shfl_xor reduce; ufg -> LDS (cross-wave),
//     t2 stays in-register (wave-local, __shfl broadcast).   f32 precision
//     (better than old k0 bf16-MFMA path).
//   barrier #0 (drains all vmcnt: items in LDS + sUFG visible) -> phase B
//   (MFMA union + fused epilogue) -> barrier #1 (cross-wave reduce) -> vr ->
//   phase C scoring from prefetched regs -> barrier #2 -> store.
// ===========================================================================
__global__ __launch_bounds__(256, 4) void k_all(
    const int* __restrict__ uid_g, const int* __restrict__ iid_g,
    const int* __restrict__ tgt_g,
    const float* __restrict__ user_table, const float* __restrict__ item_table,
    const float* __restrict__ W2, const float* __restrict__ b2,
    const float* __restrict__ Wu, const float* __restrict__ bu,
    const float* __restrict__ bi, const float* __restrict__ igu,
    const float* __restrict__ Wi, const float* __restrict__ igi,
    float* __restrict__ out)
{
    const int tid = threadIdx.x;
    const int lane = tid & 63;
    const int w = tid >> 6;                 // wave id 0..3 == union mi
    const int c = lane & 15, q = lane >> 4;
    const int j = tid & 15, gg = tid >> 4;  // scoring: 16 groups of 16 lanes
    const int b = blockIdx.x;

    __shared__ __align__(16) float sE[4][16 * DD];  // wave-private item quadrants
    __shared__ __align__(16) float sB[128];         // b2 staged
    __shared__ __align__(16) float sUu[DD];         // user row (for vr)
    __shared__ __align__(16) float sUFG[DD];        // ufg vector (cross-wave)
    __shared__ __align__(16) float sU[4 * DD];      // per-wave unum partials
    __shared__ __align__(16) float sS[4 * DD];      // per-wave sip partials
    __shared__ float sI[4];                         // per-wave isum partials
    __shared__ float sOut[112];

    const int* iidp = iid_g + b * LL;
    const int* tgtp = tgt_g + b * NT;
    float* sEw = sE[w];
    const int uid = uid_g[b];

    // ---- item ids for THIS wave's 16 rows (clamped) ----
    int iid4[4];
#pragma unroll
    for (int s = 0; s < 4; s++) {
        const int r = w * 16 + 4 * s + q;
        iid4[s] = iidp[r < LL ? r : LL - 1];
    }
    // ---- tgt ids (group-major, for W2 prefetch) ----
    int tt[7];
#pragma unroll
    for (int i = 0; i < 7; i++) {
        const int ts = i * 16 + gg;             // 0..111 (100..111 = pad)
        tt[i] = tgtp[ts < NT ? ts : NT - 1];
    }

    // ---- async item gather into own quadrant: local rows 4s..4s+3, 16B
    //      chunks XOR-swizzled by (local_row & 7) ----
#pragma unroll
    for (int s = 0; s < 4; s++) {
        const int rl = 4 * s + q;
        const int j2 = c ^ (rl & 7);
        glds16(item_table + (size_t)iid4[s] * DD + j2 * 4, sEw + s * 256);
    }

    // ---- W2 prefetch to regs (consumed in phase C) ----
    float4 wv[7];
#pragma unroll
    for (int i = 0; i < 7; i++)
        wv[i] = *(const float4*)(W2 + (size_t)tt[i] * DD + j * 4);

    // ---- small staged loads, spread across waves ----
    if (w == 1)
        glds4(user_table + (size_t)uid * DD + lane, sUu);
    if (w == 2) {
        const int tb = lane < NT ? lane : NT - 1;
        glds4(b2 + tgtp[tb], sB);
    }
    if (w == 3) {
        const int sl = 64 + lane;
        const int tb = sl < NT ? sl : NT - 1;
        glds4(b2 + tgtp[tb], sB + 64);
    }

    // ---- in-block ufg/t2 (was k0): 4-lane groups, 16 k's each ----
    // lane -> nl = lane>>2 (output idx within wave range), kq = lane&3
    const int nl = lane >> 2, kq = lane & 3, k0i = kq * 16;
    const int nglob = w * 16 + nl;          // ufg output index (0..63)
    const int ltc = nglob < LL ? nglob : LL - 1;  // clamped t2 col
    const float* urow = user_table + (size_t)uid * DD;

    float u16[16], wu16[16];
#pragma unroll
    for (int m = 0; m < 4; m++)
        *(float4*)&u16[m * 4] = *(const float4*)(urow + k0i + m * 4);
#pragma unroll
    for (int m = 0; m < 4; m++)
        *(float4*)&wu16[m * 4] = *(const float4*)(Wu + nglob * DD + k0i + m * 4);

    float ufg_p = 0.f, t2_p = 0.f;
#pragma unroll
    for (int m = 0; m < 16; m++) {
        ufg_p += u16[m] * wu16[m];
        t2_p  += u16[m] * igu[(k0i + m) * LL + ltc];
    }
    ufg_p += __shfl_xor(ufg_p, 1); ufg_p += __shfl_xor(ufg_p, 2);
    t2_p  += __shfl_xor(t2_p, 1);  t2_p  += __shfl_xor(t2_p, 2);
    const float t2full = t2_p;              // t2[w*16+nl], all 4 lanes
    if ((lane & 3) == 0)
        sUFG[nglob] = ufg_p + bu[nglob] + bi[nglob];

    // ---- wb frags straight from f32 Wi (L2-hot) + igi ----
    bf16x8 wb[4][2];
#pragma unroll
    for (int ni = 0; ni < 4; ni++)
#pragma unroll
        for (int kf = 0; kf < 2; kf++) {
            float tmp[8];
            const float* src = Wi + (ni * 16 + c) * DD + kf * 32 + q * 8;
            *(float4*)&tmp[0] = *(const float4*)src;
            *(float4*)&tmp[4] = *(const float4*)(src + 4);
            wb[ni][kf] = cvt8f(tmp);
        }
    float igi4[4];
#pragma unroll
    for (int ni = 0; ni < 4; ni++) igi4[ni] = igi[ni * 16 + c];

    __syncthreads();   // barrier #0: drains vmcnt (items in LDS) + sUFG visible

    // ---- ufg slice (broadcast ds_reads, conflict-free) ----
    float ufg4[4];
#pragma unroll
    for (int ni = 0; ni < 4; ni++) ufg4[ni] = sUFG[ni * 16 + c];

    // ---- A-frags from own quadrant (deswizzled), invalid rows zeroed ----
    bf16x8 ea[2];
    {
        const int grow = w * 16 + c;
        const float* rowp = sEw + c * DD;
        const int s7 = c & 7;
#pragma unroll
        for (int kf = 0; kf < 2; kf++) {
            float tmp[8];
            const int ch0 = (kf * 8 + 2 * q) ^ s7;
            const int ch1 = (kf * 8 + 2 * q + 1) ^ s7;
            *(float4*)&tmp[0] = *(const float4*)(rowp + ch0 * 4);
            *(float4*)&tmp[4] = *(const float4*)(rowp + ch1 * 4);
            if (grow >= LL) {
#pragma unroll
                for (int i = 0; i < 8; i++) tmp[i] = 0.f;
            }
            ea[kf] = cvt8f(tmp);
        }
    }

    // ---- union MFMA + fused per-reg epilogue ----
    float unum[4] = {0.f, 0.f, 0.f, 0.f};
    float sip[4]  = {0.f, 0.f, 0.f, 0.f};
    float isum = 0.f;
    {
        f32x4 acc[4];
#pragma unroll
        for (int ni = 0; ni < 4; ni++) {
            f32x4 a = {0.f, 0.f, 0.f, 0.f};
            a = __builtin_amdgcn_mfma_f32_16x16x32_bf16(ea[0], wb[ni][0], a, 0, 0, 0);
            a = __builtin_amdgcn_mfma_f32_16x16x32_bf16(ea[1], wb[ni][1], a, 0, 0, 0);
            acc[ni] = a;
        }
#pragma unroll
        for (int reg = 0; reg < 4; reg++) {
            const int lrl = q * 4 + reg;            // local row in quadrant
            const int valid = (w * 16 + lrl < LL);
            const int s7 = lrl & 7;
            float gd[4];
            float t1 = 0.f;
#pragma unroll
            for (int ni = 0; ni < 4; ni++) {
                const int phys = (4 * ni + (c >> 2)) ^ s7;
                const float ev = sEw[lrl * DD + phys * 4 + (c & 3)];
                const float e = valid ? ev : 0.f;
                const float g = sigmoidf_(acc[ni][reg] + ufg4[ni]);
                gd[ni] = e * g;
                t1 += gd[ni] * igi4[ni];
                sip[ni] += e;
            }
            t1 += __shfl_xor(t1, 1); t1 += __shfl_xor(t1, 2);
            t1 += __shfl_xor(t1, 4); t1 += __shfl_xor(t1, 8);
            const float t2a = __shfl(t2full, (q * 4 + reg) << 2);
            const float inst = valid ? sigmoidf_(t1 + t2a) : 0.f;
            isum += inst;
#pragma unroll
            for (int ni = 0; ni < 4; ni++)
                unum[ni] += gd[ni] * inst;
        }
    }

    // intra-wave: sum over q groups, then pick ni == q -> value for d = lane
#pragma unroll
    for (int ni = 0; ni < 4; ni++) {
        unum[ni] += __shfl_xor(unum[ni], 16); unum[ni] += __shfl_xor(unum[ni], 32);
        sip[ni]  += __shfl_xor(sip[ni], 16);  sip[ni]  += __shfl_xor(sip[ni], 32);
    }
    isum += __shfl_xor(isum, 16); isum += __shfl_xor(isum, 32);

    const float un = (q == 0) ? unum[0] : (q == 1) ? unum[1] : (q == 2) ? unum[2] : unum[3];
    const float si = (q == 0) ? sip[0]  : (q == 1) ? sip[1]  : (q == 2) ? sip[2]  : sip[3];
    sU[w * DD + lane] = un;
    sS[w * DD + lane] = si;
    if (lane == 0) sI[w] = isum;
    __syncthreads();   // barrier #1: cross-wave reduce (also orders sUu/sB)

    // ---- redundant all-thread reduce -> vr (user-vector slice dims j*4..) ----
    float4 vr;
    {
        const float4 u0 = *(const float4*)&sU[0 * DD + j * 4];
        const float4 u1 = *(const float4*)&sU[1 * DD + j * 4];
        const float4 u2 = *(const float4*)&sU[2 * DD + j * 4];
        const float4 u3 = *(const float4*)&sU[3 * DD + j * 4];
        const float4 s0 = *(const float4*)&sS[0 * DD + j * 4];
        const float4 s1 = *(const float4*)&sS[1 * DD + j * 4];
        const float4 s2 = *(const float4*)&sS[2 * DD + j * 4];
        const float4 s3 = *(const float4*)&sS[3 * DD + j * 4];
        const float4 uu = *(const float4*)&sUu[j * 4];
        const float rist = __builtin_amdgcn_rcpf(sI[0] + sI[1] + sI[2] + sI[3]);
        vr.x = uu.x + (u0.x + u1.x + u2.x + u3.x) * rist + (s0.x + s1.x + s2.x + s3.x);
        vr.y = uu.y + (u0.y + u1.y + u2.y + u3.y) * rist + (s0.y + s1.y + s2.y + s3.y);
        vr.z = uu.z + (u0.z + u1.z + u2.z + u3.z) * rist + (s0.z + s1.z + s2.z + s3.z);
        vr.w = uu.w + (u0.w + u1.w + u2.w + u3.w) * rist + (s0.w + s1.w + s2.w + s3.w);
    }

    // ---- scoring from prefetched registers ----
#pragma unroll
    for (int i = 0; i < 7; i++) {
        const int ts = i * 16 + gg;
        float s = wv[i].x * vr.x + wv[i].y * vr.y + wv[i].z * vr.z + wv[i].w * vr.w;
        s += __shfl_xor(s, 1); s += __shfl_xor(s, 2);
        s += __shfl_xor(s, 4); s += __shfl_xor(s, 8);
        if (j == 0 && ts < NT) sOut[ts] = s + sB[ts];
    }
    __syncthreads();   // barrier #2: sOut staging
    if (tid < NT) out[b * NT + tid] = sOut[tid];
}

// ===========================================================================
extern "C" void kernel_launch(void* const* d_in, const int* in_sizes, int n_in,
                              void* d_out, int out_size, void* d_ws, size_t ws_size,
                              hipStream_t stream)
{
    const int* user_ids        = (const int*)d_in[0];
    const int* item_seq_ids    = (const int*)d_in[1];
    const int* target_item_ids = (const int*)d_in[2];
    const float* user_tab      = (const float*)d_in[3];
    const float* item_tab      = (const float*)d_in[4];
    const float* W2_tab        = (const float*)d_in[5];
    const float* b2_tab        = (const float*)d_in[6];
    const float* fg_item_W     = (const float*)d_in[7];
    const float* fg_item_b     = (const float*)d_in[8];
    const float* fg_user_W     = (const float*)d_in[9];
    const float* fg_user_b     = (const float*)d_in[10];
    const float* igi           = (const float*)d_in[11];
    const float* igu           = (const float*)d_in[12];
    float* out = (float*)d_out;

    k_all<<<NB, 256, 0, stream>>>(user_ids, item_seq_ids, target_item_ids,
                                  user_tab, item_tab, W2_tab, b2_tab,
                                  fg_user_W, fg_user_b, fg_item_b, igu,
                                  fg_item_W, igi, out);
}

// Round 8
// 158.435 us; speedup vs baseline: 1.0820x; 1.0820x over previous
//
#include <hip/hip_runtime.h>

// Problem constants
#define DD 64
#define LL 50
#define NB 4096
#define NT 100
#define NSTRM 2048   // streamer/mirror blocks appended to k0

typedef __attribute__((ext_vector_type(8))) __bf16 bf16x8;
typedef __attribute__((ext_vector_type(4))) float f32x4;

__device__ __forceinline__ float sigmoidf_(float x) {
    return __builtin_amdgcn_rcpf(1.0f + __expf(-x));
}
// round-half-up f32->bf16 pack (k0 GEMM path, kept bit-identical to round 3)
__device__ __forceinline__ unsigned pack_bf16(float hi, float lo) {
    union { float f; unsigned u; } a, b;
    a.f = hi; b.f = lo;
    return ((a.u + 0x8000u) & 0xffff0000u) | ((b.u + 0x8000u) >> 16);
}
__device__ __forceinline__ uint4 cvt8u(const float* f) {
    uint4 r;
    r.x = pack_bf16(f[1], f[0]);
    r.y = pack_bf16(f[3], f[2]);
    r.z = pack_bf16(f[5], f[4]);
    r.w = pack_bf16(f[7], f[6]);
    return r;
}
__device__ __forceinline__ bf16x8 cvt8(const float* f) {
    return __builtin_bit_cast(bf16x8, cvt8u(f));
}
// HW packed RNE convert: dst.lo = bf16(lo), dst.hi = bf16(hi)
__device__ __forceinline__ unsigned cvtpk(float lo, float hi) {
    unsigned r;
    asm("v_cvt_pk_bf16_f32 %0, %1, %2" : "=v"(r) : "v"(lo), "v"(hi));
    return r;
}
// bf16 (as ushort) -> f32
__device__ __forceinline__ float b2f(unsigned short u) {
    return __builtin_bit_cast(float, (unsigned)u << 16);
}
// async global->LDS: wave-uniform LDS base + lane*size (gfx950)
__device__ __forceinline__ void glds16(const void* g, void* l) {
    __builtin_amdgcn_global_load_lds(
        (const __attribute__((address_space(1))) void*)g,
        (__attribute__((address_space(3))) void*)l, 16, 0, 0);
}
__device__ __forceinline__ void glds4(const void* g, void* l) {
    __builtin_amdgcn_global_load_lds(
        (const __attribute__((address_space(1))) void*)g,
        (__attribute__((address_space(3))) void*)l, 4, 0, 0);
}

// ===========================================================================
// K0: blocks 0..255: batched user GEMM (16 users/block, 2 waves).
//     block 256: pack fg_item_W -> bf16 row-major (wiB).
//     blocks 257..: STREAM+MIRROR — convert item_table f32 -> bf16 mirror in
//     workspace (halves k1's item gather bytes AND leaves the mirror
//     LLC-resident: written immediately before k1, nothing evicts it), plus
//     read-warm of W2 + b2 (k1's other gather streams become LLC hits).
// ===========================================================================
__global__ __launch_bounds__(128) void k0_user(
    const int* __restrict__ uid_g, const float* __restrict__ user_table,
    const float* __restrict__ Wu, const float* __restrict__ bu,
    const float* __restrict__ bi, const float* __restrict__ igu,
    const float* __restrict__ Wi,
    const float* __restrict__ item_table, const float* __restrict__ W2,
    const float* __restrict__ b2,
    float* __restrict__ ufg_ws, float* __restrict__ t2_ws,
    unsigned short* __restrict__ wiB_ws, unsigned short* __restrict__ mir)
{
    if (blockIdx.x >= 257) {   // ---- mirror + warm ----
        const int t = (blockIdx.x - 257) * 128 + threadIdx.x;  // 0..262143
        const int stride = NSTRM * 128;
        const float4* it4 = (const float4*)item_table;  // 1,600,000 float4
        const float4* w24 = (const float4*)W2;          // 1,600,000 float4
        const float4* b24 = (const float4*)b2;          //    25,000 float4
        uint4* m4 = (uint4*)mir;                        //   800,000 uint4
#pragma unroll
        for (int k = 0; k < 4; k++) {                   // item -> bf16 mirror
            const int idx = t + k * stride;
            if (idx < 800000) {
                const float4 a = it4[2 * idx];
                const float4 bq = it4[2 * idx + 1];
                uint4 r;
                r.x = cvtpk(a.x, a.y);  r.y = cvtpk(a.z, a.w);
                r.z = cvtpk(bq.x, bq.y); r.w = cvtpk(bq.z, bq.w);
                m4[idx] = r;
            }
        }
        float acc = 0.f;
#pragma unroll
        for (int k = 0; k < 7; k++) {                   // W2 read-warm
            const int idx = t + k * stride;
            if (idx < 1600000) {
                const float4 cq = w24[idx];
                acc += (cq.x + cq.y) + (cq.z + cq.w);
            }
        }
        if (t < 25000) {                                // b2 read-warm
            const float4 d = b24[t];
            acc += (d.x + d.y) + (d.z + d.w);
        }
        asm volatile("" :: "v"(acc));   // keep loads live, no store
        return;
    }

    if (blockIdx.x == 256) {   // Wi -> bf16 pack (one wave only)
        if (threadIdx.x >= 64) return;
        const int n = threadIdx.x;
        float tmp[64];
#pragma unroll
        for (int c4 = 0; c4 < 16; c4++)
            *(float4*)&tmp[c4 * 4] = *(const float4*)(Wi + n * DD + c4 * 4);
#pragma unroll
        for (int ch = 0; ch < 8; ch++)
            *(uint4*)(wiB_ws + n * DD + ch * 8) = cvt8u(tmp + ch * 8);
        return;
    }

    const int lane = threadIdx.x & 63;
    const int wv = threadIdx.x >> 6;         // wave 0: ni 0..3, wave 1: ni 4..7
    const int c = lane & 15, q = lane >> 4;
    const int uid = uid_g[blockIdx.x * 16 + c];
    const float* urow = user_table + (size_t)uid * DD;

    bf16x8 af[2];
#pragma unroll
    for (int kf = 0; kf < 2; kf++) {
        float tmp[8];
        *(float4*)&tmp[0] = *(const float4*)(urow + kf * 32 + q * 8);
        *(float4*)&tmp[4] = *(const float4*)(urow + kf * 32 + q * 8 + 4);
        af[kf] = cvt8(tmp);
    }

#pragma unroll
    for (int ni0 = 0; ni0 < 4; ni0++) {
        const int ni = wv * 4 + ni0;
        f32x4 a = {0.f, 0.f, 0.f, 0.f};
#pragma unroll
        for (int kf = 0; kf < 2; kf++) {
            const int k0 = kf * 32 + q * 8;
            float tmp[8];
            if (ni < 4) {
                const float* src = Wu + (ni * 16 + c) * DD + k0;
                *(float4*)&tmp[0] = *(const float4*)src;
                *(float4*)&tmp[4] = *(const float4*)(src + 4);
            } else {
                const int l = ni * 16 + c - 64;
#pragma unroll
                for (int jj = 0; jj < 8; jj++)
                    tmp[jj] = (l < LL) ? igu[(k0 + jj) * LL + l] : 0.f;
            }
            a = __builtin_amdgcn_mfma_f32_16x16x32_bf16(af[kf], cvt8(tmp), a, 0, 0, 0);
        }
        const int n = ni * 16 + c;
#pragma unroll
        for (int reg = 0; reg < 4; reg++) {
            const int bo = blockIdx.x * 16 + q * 4 + reg;
            if (n < DD)           ufg_ws[bo * DD + n] = a[reg] + bu[n] + bi[n];
            else if (n < DD + LL) t2_ws[bo * DD + (n - DD)] = a[reg];
        }
    }
}

// ===========================================================================
// K1F v5: round-3 structure (wave-decoupled, proven 41.5us) with the item
//   path on the bf16 MIRROR: 2 glds16/wave (8 rows each, 128B/row), LDS item
//   tile halves to 8KB, A-frags are direct uint4 bitcasts (no cvt), epilogue
//   e reads bf16 (ds_read_u16 + shift).  XOR swizzle now at 16B-chunk
//   granularity within the 8-chunk row: phys = logical ^ (row&7).
// ===========================================================================
__global__ __launch_bounds__(256, 4) void k1_fused(
    const int* __restrict__ uid_g, const int* __restrict__ iid_g,
    const int* __restrict__ tgt_g,
    const float* __restrict__ user_table, const unsigned short* __restrict__ mir,
    const float* __restrict__ W2, const float* __restrict__ b2,
    const unsigned short* __restrict__ wiB, const float* __restrict__ igi,
    const float* __restrict__ ufg_ws, const float* __restrict__ t2_ws,
    float* __restrict__ out)
{
    const int tid = threadIdx.x;
    const int lane = tid & 63;
    const int w = tid >> 6;                 // wave id 0..3 == union mi
    const int c = lane & 15, q = lane >> 4;
    const int j = tid & 15, gg = tid >> 4;  // scoring: 16 groups of 16 lanes
    const int b = blockIdx.x;

    __shared__ __align__(16) unsigned short sE[4][16 * DD];  // bf16 quadrants
    __shared__ __align__(16) float sB[128];         // b2 staged
    __shared__ __align__(16) float sUu[DD];         // user row
    __shared__ __align__(16) float sU[4 * DD];      // per-wave unum partials
    __shared__ __align__(16) float sS[4 * DD];      // per-wave sip partials
    __shared__ float sI[4];                         // per-wave isum partials
    __shared__ float sOut[112];

    const int* iidp = iid_g + b * LL;
    const int* tgtp = tgt_g + b * NT;
    unsigned short* sEw = sE[w];

    // ---- item ids: glds16 instr s covers local rows s*8 + (lane>>3) ----
    int iid2[2];
#pragma unroll
    for (int s = 0; s < 2; s++) {
        const int r = w * 16 + s * 8 + (lane >> 3);
        iid2[s] = iidp[r < LL ? r : LL - 1];
    }
    // ---- tgt ids (group-major, for W2 prefetch) ----
    int tt[7];
#pragma unroll
    for (int i = 0; i < 7; i++) {
        const int ts = i * 16 + gg;             // 0..111 (100..111 = pad)
        tt[i] = tgtp[ts < NT ? ts : NT - 1];
    }

    // ---- async item gather (bf16 mirror): lane covers row lane>>3, chunk
    //      lane&7; logical chunk = phys ^ (row&7) pre-applied on global side ----
#pragma unroll
    for (int s = 0; s < 2; s++) {
        const int j2 = (lane & 7) ^ (lane >> 3);
        glds16(mir + (size_t)iid2[s] * DD + j2 * 8, sEw + s * 512);
    }

    // ---- W2 prefetch to regs ----
    float4 wv[7];
#pragma unroll
    for (int i = 0; i < 7; i++)
        wv[i] = *(const float4*)(W2 + (size_t)tt[i] * DD + j * 4);

    // ---- small staged loads, spread across waves ----
    if (w == 1) {
        const int uid = uid_g[b];
        glds4(user_table + (size_t)uid * DD + lane, sUu);
    }
    if (w == 2) {
        const int tb = lane < NT ? lane : NT - 1;
        glds4(b2 + tgtp[tb], sB);
    }
    if (w == 3) {
        const int sl = 64 + lane;
        const int tb = sl < NT ? sl : NT - 1;
        glds4(b2 + tgtp[tb], sB + 64);
    }

    // ---- per-b scalars + t2 slice ----
    float ufg4[4], igi4[4];
#pragma unroll
    for (int ni = 0; ni < 4; ni++) {
        ufg4[ni] = ufg_ws[b * DD + ni * 16 + c];
        igi4[ni] = igi[ni * 16 + c];
    }
    const float4 t2v = *(const float4*)(t2_ws + b * DD + w * 16 + q * 4);
    float t2a[4] = {t2v.x, t2v.y, t2v.z, t2v.w};

    // ---- wb frags (8 KB table, L2-hot) ----
    bf16x8 wb[4][2];
#pragma unroll
    for (int ni = 0; ni < 4; ni++)
#pragma unroll
        for (int kf = 0; kf < 2; kf++)
            wb[ni][kf] = __builtin_bit_cast(bf16x8,
                *(const uint4*)(wiB + (ni * 16 + c) * DD + kf * 32 + q * 8));

    // ---- wave-local drain: own glds + all reg loads complete; no barrier ----
    asm volatile("s_waitcnt vmcnt(0)" ::: "memory");
    __builtin_amdgcn_sched_barrier(0);

    // ---- A-frags: direct bitcast from bf16 LDS (deswizzled), zero invalid ----
    bf16x8 ea[2];
    {
        const int grow = w * 16 + c;
        const int s7 = c & 7;
        const unsigned short* rowp = sEw + c * DD;   // 64 bf16 = 8 chunks
        if (grow < LL) {
            ea[0] = __builtin_bit_cast(bf16x8, *(const uint4*)(rowp + ((q)     ^ s7) * 8));
            ea[1] = __builtin_bit_cast(bf16x8, *(const uint4*)(rowp + ((4 + q) ^ s7) * 8));
        } else {
            const uint4 z = {0u, 0u, 0u, 0u};
            ea[0] = __builtin_bit_cast(bf16x8, z);
            ea[1] = __builtin_bit_cast(bf16x8, z);
        }
    }

    // ---- union MFMA + fused per-reg epilogue ----
    const int chi = c >> 3, clo = c & 7;   // element d = ni*16+c -> chunk ni*2+chi, off clo
    float unum[4] = {0.f, 0.f, 0.f, 0.f};
    float sip[4]  = {0.f, 0.f, 0.f, 0.f};
    float isum = 0.f;
    {
        f32x4 acc[4];
#pragma unroll
        for (int ni = 0; ni < 4; ni++) {
            f32x4 a = {0.f, 0.f, 0.f, 0.f};
            a = __builtin_amdgcn_mfma_f32_16x16x32_bf16(ea[0], wb[ni][0], a, 0, 0, 0);
            a = __builtin_amdgcn_mfma_f32_16x16x32_bf16(ea[1], wb[ni][1], a, 0, 0, 0);
            acc[ni] = a;
        }
#pragma unroll
        for (int reg = 0; reg < 4; reg++) {
            const int lrl = q * 4 + reg;            // local row in quadrant
            const int valid = (w * 16 + lrl < LL);
            const int s7 = lrl & 7;
            float gd[4];
            float t1 = 0.f;
#pragma unroll
            for (int ni = 0; ni < 4; ni++) {
                const int pch = (ni * 2 + chi) ^ s7;
                const float ev = b2f(sEw[lrl * DD + pch * 8 + clo]);
                const float e = valid ? ev : 0.f;
                const float g = sigmoidf_(acc[ni][reg] + ufg4[ni]);
                gd[ni] = e * g;
                t1 += gd[ni] * igi4[ni];
                sip[ni] += e;
            }
            t1 += __shfl_xor(t1, 1); t1 += __shfl_xor(t1, 2);
            t1 += __shfl_xor(t1, 4); t1 += __shfl_xor(t1, 8);
            const float inst = valid ? sigmoidf_(t1 + t2a[reg]) : 0.f;
            isum += inst;
#pragma unroll
            for (int ni = 0; ni < 4; ni++)
                unum[ni] += gd[ni] * inst;
        }
    }

    // intra-wave: sum over q groups, then pick ni == q -> value for d = lane
#pragma unroll
    for (int ni = 0; ni < 4; ni++) {
        unum[ni] += __shfl_xor(unum[ni], 16); unum[ni] += __shfl_xor(unum[ni], 32);
        sip[ni]  += __shfl_xor(sip[ni], 16);  sip[ni]  += __shfl_xor(sip[ni], 32);
    }
    isum += __shfl_xor(isum, 16); isum += __shfl_xor(isum, 32);

    const float un = (q == 0) ? unum[0] : (q == 1) ? unum[1] : (q == 2) ? unum[2] : unum[3];
    const float si = (q == 0) ? sip[0]  : (q == 1) ? sip[1]  : (q == 2) ? sip[2]  : sip[3];
    sU[w * DD + lane] = un;
    sS[w * DD + lane] = si;
    if (lane == 0) sI[w] = isum;
    __syncthreads();   // barrier 1: cross-wave reduce (also orders sUu/sB)

    // ---- redundant all-thread reduce -> vr ----
    float4 vr;
    {
        const float4 u0 = *(const float4*)&sU[0 * DD + j * 4];
        const float4 u1 = *(const float4*)&sU[1 * DD + j * 4];
        const float4 u2 = *(const float4*)&sU[2 * DD + j * 4];
        const float4 u3 = *(const float4*)&sU[3 * DD + j * 4];
        const float4 s0 = *(const float4*)&sS[0 * DD + j * 4];
        const float4 s1 = *(const float4*)&sS[1 * DD + j * 4];
        const float4 s2 = *(const float4*)&sS[2 * DD + j * 4];
        const float4 s3 = *(const float4*)&sS[3 * DD + j * 4];
        const float4 uu = *(const float4*)&sUu[j * 4];
        const float rist = __builtin_amdgcn_rcpf(sI[0] + sI[1] + sI[2] + sI[3]);
        vr.x = uu.x + (u0.x + u1.x + u2.x + u3.x) * rist + (s0.x + s1.x + s2.x + s3.x);
        vr.y = uu.y + (u0.y + u1.y + u2.y + u3.y) * rist + (s0.y + s1.y + s2.y + s3.y);
        vr.z = uu.z + (u0.z + u1.z + u2.z + u3.z) * rist + (s0.z + s1.z + s2.z + s3.z);
        vr.w = uu.w + (u0.w + u1.w + u2.w + u3.w) * rist + (s0.w + s1.w + s2.w + s3.w);
    }

    // ---- scoring from prefetched registers ----
#pragma unroll
    for (int i = 0; i < 7; i++) {
        const int ts = i * 16 + gg;
        float s = wv[i].x * vr.x + wv[i].y * vr.y + wv[i].z * vr.z + wv[i].w * vr.w;
        s += __shfl_xor(s, 1); s += __shfl_xor(s, 2);
        s += __shfl_xor(s, 4); s += __shfl_xor(s, 8);
        if (j == 0 && ts < NT) sOut[ts] = s + sB[ts];
    }
    __syncthreads();   // barrier 2: sOut staging
    if (tid < NT) out[b * NT + tid] = sOut[tid];
}

// ===========================================================================
extern "C" void kernel_launch(void* const* d_in, const int* in_sizes, int n_in,
                              void* d_out, int out_size, void* d_ws, size_t ws_size,
                              hipStream_t stream)
{
    const int* user_ids        = (const int*)d_in[0];
    const int* item_seq_ids    = (const int*)d_in[1];
    const int* target_item_ids = (const int*)d_in[2];
    const float* user_tab      = (const float*)d_in[3];
    const float* item_tab      = (const float*)d_in[4];
    const float* W2_tab        = (const float*)d_in[5];
    const float* b2_tab        = (const float*)d_in[6];
    const float* fg_item_W     = (const float*)d_in[7];
    const float* fg_item_b     = (const float*)d_in[8];
    const float* fg_user_W     = (const float*)d_in[9];
    const float* fg_user_b     = (const float*)d_in[10];
    const float* igi           = (const float*)d_in[11];
    const float* igu           = (const float*)d_in[12];
    float* out = (float*)d_out;

    float* ufg_ws = (float*)d_ws;                       // [4096][64] f32
    float* t2_ws  = ufg_ws + NB * DD;                   // [4096][64] f32
    unsigned short* wiB_ws = (unsigned short*)(t2_ws + NB * DD);  // [64][64] bf16
    unsigned short* mir    = wiB_ws + 64 * 64;          // [100000][64] bf16 mirror

    k0_user<<<257 + NSTRM, 128, 0, stream>>>(
        user_ids, user_tab, fg_user_W, fg_user_b, fg_item_b, igu, fg_item_W,
        item_tab, W2_tab, b2_tab,
        ufg_ws, t2_ws, wiB_ws, mir);
    k1_fused<<<NB, 256, 0, stream>>>(user_ids, item_seq_ids, target_item_ids,
                                     user_tab, mir, W2_tab, b2_tab,
                                     wiB_ws, igi, ufg_ws, t2_ws, out);
}